// Round 7
// baseline (178.319 us; speedup 1.0000x reference)
//
#include <hip/hip_runtime.h>

#define NB    16      // batch
#define NN    2000    // rois per image
#define NC    81      // classes
#define NPAD  2048    // padded sort size (worst case)
#define MAXI  100     // max instances
#define MINC  0.7f
#define NMST  0.3f
#define NEGV  -1000000000.0f
#define BT    512     // block threads
#define NWAVE (BT/64)
#define PPI   63      // prep blocks per image (63*32 >= 2000)
#define NPREP (NB * PPI)

#define WS_BOX_OFF   0
#define WS_KEY_OFF   (NB * NN * 16)                 // 512000
#define WS_DONE_OFF  (WS_KEY_OFF + NB * NN * 8)     // 768000
#define WS_NEEDED    (WS_DONE_OFF + 64)             // 768064

// monotone order-preserving float->uint encoding
__device__ __forceinline__ unsigned ordf(float f) {
    unsigned u = __float_as_uint(f);
    return (u & 0x80000000u) ? ~u : (u | 0x80000000u);
}
__device__ __forceinline__ float unordf(unsigned u) {
    unsigned b = (u & 0x80000000u) ? (u ^ 0x80000000u) : ~u;
    return __uint_as_float(b);
}

// register bitonic compare-exchange across lanes (64-bit key via 2x shfl_xor)
__device__ __forceinline__ unsigned long long cx64(unsigned long long k, int j,
                                                   bool desc, int lane) {
    unsigned lo = __shfl_xor((unsigned)k, j, 64);
    unsigned hi = __shfl_xor((unsigned)(k >> 32), j, 64);
    unsigned long long p = ((unsigned long long)hi << 32) | lo;
    bool lower    = ((lane & j) == 0);
    bool take_max = (lower == desc);
    return ((p > k) == take_max) ? p : k;
}

// key layout: [63:32] ordf(masked_score) | [18:8] (2047 - i) | [7:0] class
// (bits below the unique inv-index never affect the stable sort order)

// ---------------- fused kernel ------------------------------------------
// blocks [0, NB):          det2 consumer for image b = blockIdx.x
//                          (spin-waits on done[b] == PPI, then runs)
// blocks [NB, NB+NPREP):   prep producer; round-4 prep shape:
//                          16 lanes/roi, 32 rois per block, coalesced.
// Deadlock-free: 16 spinners << resident capacity (whole grid of 1024
// blocks is co-resident at ~24KB LDS / 512 thr = 4 blocks/CU * 256 CU).
__global__ __launch_bounds__(BT)
void fused_kernel(const float* __restrict__ rois,
                  const float* __restrict__ probs,
                  const float* __restrict__ deltas,
                  const float* __restrict__ meta,
                  float4* __restrict__ wbox,
                  unsigned long long* __restrict__ wkey,
                  unsigned int* __restrict__ done,
                  float* __restrict__ out) {
    __shared__ unsigned long long skey[NPAD];   // 16384 B
    __shared__ unsigned char sup[NPAD];         // 2048 B
    __shared__ unsigned short pool[NPAD];       // 4096 B (ranks grouped by class)
    __shared__ int hist[82], cstart[82], cnt[82];
    __shared__ int out_rank[MAXI];
    __shared__ int sK, nsurv;

    const int bi = blockIdx.x;

    if (bi >= NB) {
        // ================= producer: prep 32 rois (16 lanes each) =========
        const int pbi   = bi - NB;
        const int b     = pbi / PPI;
        const int chunk = pbi - b * PPI;
        const int g = threadIdx.x >> 4;
        const int l = threadIdx.x & 15;
        const int i = chunk * 32 + g;
        if (i < NN) {
            const size_t r = (size_t)b * NN + i;
            const float* prow = probs + r * NC;
            float best = -1.0f; int cb = 0;
            for (int c = l; c < NC; c += 16) {
                float p = prow[c];
                if (p > best) { best = p; cb = c; }   // first-max
            }
            #pragma unroll
            for (int off = 8; off; off >>= 1) {
                float pb = __shfl_xor(best, off, 16);
                int   co = __shfl_xor(cb,   off, 16);
                if (pb > best || (pb == best && co < cb)) { best = pb; cb = co; }
            }
            if (l == 0) {
                const int MS = 12 + NC;
                const float ih = meta[4], iw = meta[5];
                const float sy = ih - 1.0f, sx = iw - 1.0f;
                const float wy1 = (meta[(size_t)b * MS + 7]        ) / sy;
                const float wx1 = (meta[(size_t)b * MS + 8]        ) / sx;
                const float wy2 = (meta[(size_t)b * MS + 9]  - 1.0f) / sy;
                const float wx2 = (meta[(size_t)b * MS + 10] - 1.0f) / sx;

                const float* drow = deltas + (r * NC + cb) * 4;
                float dy = drow[0] * 0.1f, dx = drow[1] * 0.1f;
                float dh = drow[2] * 0.2f, dw = drow[3] * 0.2f;

                const float4 r4 = *(const float4*)(rois + r * 4);
                float h  = r4.z - r4.x;
                float w  = r4.w - r4.y;
                float cy = r4.x + 0.5f * h;
                float cx = r4.y + 0.5f * w;
                cy = cy + dy * h;
                cx = cx + dx * w;
                h  = h * expf(dh);
                w  = w * expf(dw);
                float y1 = fminf(fmaxf(cy - 0.5f * h, wy1), wy2);
                float x1 = fminf(fmaxf(cx - 0.5f * w, wx1), wx2);
                float y2 = fminf(fmaxf(cy + 0.5f * h, wy1), wy2);
                float x2 = fminf(fmaxf(cx + 0.5f * w, wx1), wx2);

                wbox[r] = make_float4(y1, x1, y2, x2);
                bool kept = (cb > 0) && (best >= MINC);
                float msc = kept ? best : NEGV;
                wkey[r] = ((unsigned long long)ordf(msc) << 32)
                        | (unsigned long long)(((unsigned)(2047 - i) << 8)
                                               | (unsigned)cb);
            }
        }
        __threadfence();            // release this block's global stores
        __syncthreads();
        if (threadIdx.x == 0) atomicAdd(&done[b], 1u);
        return;
    }

    // ================= consumer: det2 for image b ==========================
    const int b = bi;
    if (threadIdx.x == 0) {
        while (atomicAdd(&done[b], 0u) < (unsigned)PPI) {}
        __threadfence();            // acquire: make producer stores visible
    }
    __syncthreads();

    const int tid  = threadIdx.x;
    const int lane = tid & 63;
    const int wv   = tid >> 6;

    for (int c = tid; c < 82; c += BT) { hist[c] = 0; cnt[c] = 0; }
    if (tid == 0) { sK = 0; nsurv = 0; }
    __syncthreads();

    // ---- compaction of kept keys (ballot-aggregated, unordered)
    const unsigned minc_ord = ordf(MINC);
    for (int base = 0; base < NN; base += BT) {
        int i = base + tid;
        unsigned long long k = 0ull; bool kept = false;
        if (i < NN) {
            k = wkey[(size_t)b * NN + i];
            kept = ((unsigned)(k >> 32) >= minc_ord);
        }
        unsigned long long m = __ballot(kept);
        int c64 = __popcll(m);
        int basep = 0;
        if (lane == 0 && c64) basep = atomicAdd(&sK, c64);
        basep = __shfl(basep, 0, 64);
        if (kept) skey[basep + __popcll(m & ((1ull << lane) - 1))] = k;
    }
    __syncthreads();
    const int K = sK;
    int P = 0;
    if (K > 0) { P = 64; while (P < K) P <<= 1; }   // min 64 for register sort
    for (int t = K + tid; t < P; t += BT) skey[t] = 0ull;  // pad sorts last
    __syncthreads();

    // ---- bitonic sort, descending; register chunks + LDS merges ----
    if (P > 0 && P <= 64 * NWAVE) {
        const int nch = P >> 6;
        const int e   = (wv << 6) + lane;
        unsigned long long k = 0ull;
        if (wv < nch) {
            k = skey[e];
            #pragma unroll
            for (int kk2 = 2; kk2 <= 64; kk2 <<= 1) {
                #pragma unroll
                for (int j = 32; j; j >>= 1) {
                    if (j < kk2) k = cx64(k, j, ((e & kk2) == 0), lane);
                }
            }
            skey[e] = k;
        }
        __syncthreads();
        for (int kk = 128; kk <= P; kk <<= 1) {
            for (int j = kk >> 1; j >= 64; j >>= 1) {
                int jm = j - 1;
                for (int p = tid; p < (P >> 1); p += BT) {
                    int t  = ((p & ~jm) << 1) | (p & jm);
                    int ix = t + j;
                    unsigned long long a = skey[t], c2 = skey[ix];
                    bool desc = ((t & kk) == 0);
                    if ((a < c2) == desc) { skey[t] = c2; skey[ix] = a; }
                }
                __syncthreads();
            }
            if (wv < nch) {
                k = skey[e];
                const bool desc = ((e & kk) == 0);
                #pragma unroll
                for (int j = 32; j; j >>= 1) k = cx64(k, j, desc, lane);
                skey[e] = k;
            }
            __syncthreads();
        }
    } else if (P > 0) {
        for (int kk = 2; kk <= P; kk <<= 1) {
            for (int j = kk >> 1; j > 0; j >>= 1) {
                int jm = j - 1;
                for (int p = tid; p < (P >> 1); p += BT) {
                    int t  = ((p & ~jm) << 1) | (p & jm);
                    int ix = t + j;
                    unsigned long long a = skey[t], c2 = skey[ix];
                    bool desc = ((t & kk) == 0);
                    if ((a < c2) == desc) { skey[t] = c2; skey[ix] = a; }
                }
                __syncthreads();
            }
        }
    }

    // ---- sup init + class histogram (class from key low byte)
    for (int r2 = tid; r2 < K; r2 += BT) {
        sup[r2] = 0;
        atomicAdd(&hist[(int)(skey[r2] & 0xFF)], 1);
    }
    __syncthreads();

    // ---- exclusive prefix over 82 class bins (wave 0, 2 bins/lane)
    if (wv == 0) {
        int c0 = 2 * lane, c1 = c0 + 1;
        int h0 = (c0 < 82) ? hist[c0] : 0;
        int h1 = (c1 < 82) ? hist[c1] : 0;
        int s = h0 + h1, sc = s;
        #pragma unroll
        for (int off = 1; off < 64; off <<= 1) {
            int v = __shfl_up(sc, off, 64);
            if (lane >= off) sc += v;
        }
        int excl = sc - s;
        if (c0 < 82) cstart[c0] = excl;
        if (c1 < 82) cstart[c1] = excl + h0;
    }
    __syncthreads();

    // ---- build per-class rank lists in rank order (wave 0, match-any trick)
    if (wv == 0) {
        for (int ch = 0; ch < K; ch += 64) {
            int r2 = ch + lane;
            bool v = r2 < K;
            int c = v ? (int)(skey[r2] & 0xFF) : 127;
            unsigned long long m = ~0ull;
            #pragma unroll
            for (int kb = 0; kb < 7; ++kb) {
                unsigned long long bk = __ballot((c >> kb) & 1);
                m &= ((c >> kb) & 1) ? bk : ~bk;
            }
            int leader = __ffsll(m) - 1;
            int before = __popcll(m & ((1ull << lane) - 1));
            int basec = 0;
            if (v && lane == leader) basec = atomicAdd(&cnt[c], __popcll(m));
            basec = __shfl(basec, leader, 64);
            if (v) pool[cstart[c] + basec + before] = (unsigned short)r2;
        }
    }
    __syncthreads();

    // ---- per-class NMS: classes strided over 8 waves; register chain;
    //      boxes read directly from global (L2/L3) via key index bits
    for (int c = 1 + wv; c < 82; c += NWAVE) {
        int s0 = cstart[c], n = hist[c];
        if (n <= 1) continue;
        if (n <= 64) {
            int ri = 0; float4 bi2 = make_float4(0.f,0.f,0.f,0.f);
            float ai = 0.f; bool alive = false;
            if (lane < n) {
                ri = pool[s0 + lane];
                unsigned low = (unsigned)(skey[ri] & 0xFFFFFFFFull);
                int oi = 2047 - (int)((low >> 8) & 0x7FF);
                bi2 = wbox[(size_t)b * NN + oi];
                ai = (bi2.z - bi2.x) * (bi2.w - bi2.y);
                alive = true;
            }
            unsigned long long cand = __ballot(alive);
            while (cand) {
                int curl = __ffsll(cand) - 1;
                float cy1 = __shfl(bi2.x, curl, 64);
                float cx1 = __shfl(bi2.y, curl, 64);
                float cy2 = __shfl(bi2.z, curl, 64);
                float cx2 = __shfl(bi2.w, curl, 64);
                float ca  = __shfl(ai,   curl, 64);
                float yy1 = fmaxf(cy1, bi2.x);
                float xx1 = fmaxf(cx1, bi2.y);
                float yy2 = fminf(cy2, bi2.z);
                float xx2 = fminf(cx2, bi2.w);
                float inter = fmaxf(yy2 - yy1, 0.0f) * fmaxf(xx2 - xx1, 0.0f);
                float iou = inter / (ca + ai - inter + 1e-12f);
                bool kill = alive && (lane > curl) && (iou > NMST);
                unsigned long long km = __ballot(kill);
                if (kill) alive = false;
                cand &= ~km;
                cand &= ~(1ull << curl);
            }
            if (lane < n && !alive) sup[ri] = 1;
        } else {
            // fallback: serial-i / parallel-j within the wave (n > 64)
            volatile unsigned char* vsup = sup;
            for (int ii = 0; ii < n; ++ii) {
                int ri = pool[s0 + ii];
                if (vsup[ri]) continue;
                unsigned lowi = (unsigned)(skey[ri] & 0xFFFFFFFFull);
                float4 bi2 = wbox[(size_t)b * NN + (2047 - (int)((lowi >> 8) & 0x7FF))];
                float ai = (bi2.z - bi2.x) * (bi2.w - bi2.y);
                for (int jj = ii + 1 + lane; jj < n; jj += 64) {
                    int rj = pool[s0 + jj];
                    unsigned lowj = (unsigned)(skey[rj] & 0xFFFFFFFFull);
                    float4 bj = wbox[(size_t)b * NN + (2047 - (int)((lowj >> 8) & 0x7FF))];
                    float yy1 = fmaxf(bi2.x, bj.x);
                    float xx1 = fmaxf(bi2.y, bj.y);
                    float yy2 = fminf(bi2.z, bj.z);
                    float xx2 = fminf(bi2.w, bj.w);
                    float inter = fmaxf(yy2 - yy1, 0.0f) * fmaxf(xx2 - xx1, 0.0f);
                    float aj = (bj.z - bj.x) * (bj.w - bj.y);
                    float iou = inter / (ai + aj - inter + 1e-12f);
                    if (iou > NMST) vsup[rj] = 1;
                }
            }
        }
    }
    __syncthreads();

    // ---- first 100 survivors in rank order (wave 0, ballot compaction)
    if (wv == 0) {
        int total = 0;
        for (int ch = 0; ch < K && total < MAXI; ch += 64) {
            int r2 = ch + lane;
            bool alivex = (r2 < K) && !sup[r2];
            unsigned long long m = __ballot(alivex);
            int pos = total + __popcll(m & ((1ull << lane) - 1));
            if (alivex && pos < MAXI) out_rank[pos] = r2;
            total += __popcll(m);
        }
        if (lane == 0) nsurv = total < MAXI ? total : MAXI;
    }
    __syncthreads();

    // ---- output [y1,x1,y2,x2,class,score], zero-padded
    const int ns = nsurv;
    for (int o = tid; o < MAXI; o += BT) {
        float v0=0.f,v1=0.f,v2=0.f,v3=0.f,v4=0.f,v5=0.f;
        if (o < ns) {
            int r2 = out_rank[o];
            unsigned long long kr = skey[r2];
            unsigned low = (unsigned)(kr & 0xFFFFFFFFull);
            int oi = 2047 - (int)((low >> 8) & 0x7FF);
            float4 bo = wbox[(size_t)b * NN + oi];
            v0 = bo.x; v1 = bo.y; v2 = bo.z; v3 = bo.w;
            v4 = (float)(int)(low & 0xFF);
            v5 = unordf((unsigned)(kr >> 32));
        }
        float* op = out + ((size_t)b * MAXI + o) * 6;
        op[0]=v0; op[1]=v1; op[2]=v2; op[3]=v3; op[4]=v4; op[5]=v5;
    }
}

// ---------------- fallback: monolithic kernel (if ws too small) -----------
__global__ __launch_bounds__(256)
void det_mono_kernel(const float* __restrict__ rois,
                     const float* __restrict__ probs,
                     const float* __restrict__ deltas,
                     const float* __restrict__ meta,
                     float* __restrict__ out) {
    __shared__ unsigned long long key[NPAD];
    __shared__ float4 sbox[NN];
    __shared__ unsigned char scls[NN];
    __shared__ unsigned char sup[NPAD];
    __shared__ int out_rank[MAXI];
    __shared__ int sK;
    __shared__ int nsurv;

    const int b   = blockIdx.x;
    const int tid = threadIdx.x;
    const int MSTRIDE = 12 + NC;

    if (tid == 0) { sK = 0; nsurv = 0; }

    const float ih = meta[4], iw = meta[5];
    const float sy = ih - 1.0f, sx = iw - 1.0f;
    const float wy1 = (meta[(size_t)b * MSTRIDE + 7]) / sy;
    const float wx1 = (meta[(size_t)b * MSTRIDE + 8]) / sx;
    const float wy2 = (meta[(size_t)b * MSTRIDE + 9] - 1.0f) / sy;
    const float wx2 = (meta[(size_t)b * MSTRIDE + 10] - 1.0f) / sx;

    for (int i = tid; i < NN; i += 256) {
        const float* prow = probs + ((size_t)b * NN + i) * NC;
        float best = prow[0];
        int cb = 0;
        #pragma unroll
        for (int c = 1; c < NC; ++c) {
            float p = prow[c];
            if (p > best) { best = p; cb = c; }
        }
        const float* drow = deltas + (((size_t)b * NN + i) * NC + cb) * 4;
        float dy = drow[0] * 0.1f, dx = drow[1] * 0.1f;
        float dh = drow[2] * 0.2f, dw = drow[3] * 0.2f;
        const float4 r4 = *(const float4*)(rois + ((size_t)b * NN + i) * 4);
        float h  = r4.z - r4.x;
        float w  = r4.w - r4.y;
        float cy = r4.x + 0.5f * h;
        float cx = r4.y + 0.5f * w;
        cy = cy + dy * h;
        cx = cx + dx * w;
        h  = h * expf(dh);
        w  = w * expf(dw);
        float y1 = fminf(fmaxf(cy - 0.5f * h, wy1), wy2);
        float x1 = fminf(fmaxf(cx - 0.5f * w, wx1), wx2);
        float y2 = fminf(fmaxf(cy + 0.5f * h, wy1), wy2);
        float x2 = fminf(fmaxf(cx + 0.5f * w, wx1), wx2);
        sbox[i] = make_float4(y1, x1, y2, x2);
        scls[i] = (unsigned char)cb;
        bool kept = (cb > 0) && (best >= MINC);
        float msc = kept ? best : NEGV;
        key[i] = ((unsigned long long)ordf(msc) << 32)
               | (unsigned long long)(0xFFFFFFFFu - (unsigned)i);
    }
    for (int i = NN + tid; i < NPAD; i += 256) key[i] = 0ull;
    __syncthreads();

    for (int k = 2; k <= NPAD; k <<= 1) {
        for (int j = k >> 1; j > 0; j >>= 1) {
            for (int t = tid; t < NPAD; t += 256) {
                int ix = t ^ j;
                if (ix > t) {
                    unsigned long long a = key[t], c = key[ix];
                    bool descend = ((t & k) == 0);
                    if ((a < c) == descend) { key[t] = c; key[ix] = a; }
                }
            }
            __syncthreads();
        }
    }

    const unsigned minc_ord = ordf(MINC);
    for (int r = tid; r < NPAD; r += 256) {
        unsigned su = (unsigned)(key[r] >> 32);
        bool kept = (su >= minc_ord);
        sup[r] = kept ? 0 : 1;
        if (kept) atomicAdd(&sK, 1);
    }
    __syncthreads();
    const int K = sK;

    for (int i = 0; i < K; ++i) {
        __syncthreads();
        if (nsurv >= MAXI) break;
        if (sup[i]) continue;
        unsigned long long ki = key[i];
        int oi = (int)(0xFFFFFFFFu - (unsigned)(ki & 0xFFFFFFFFull));
        float4 bi = sbox[oi];
        int ci = scls[oi];
        float ai = (bi.z - bi.x) * (bi.w - bi.y);
        for (int jr = i + 1 + tid; jr < K; jr += 256) {
            int oj = (int)(0xFFFFFFFFu - (unsigned)(key[jr] & 0xFFFFFFFFull));
            if ((int)scls[oj] != ci) continue;
            float4 bj = sbox[oj];
            float yy1 = fmaxf(bi.x, bj.x);
            float xx1 = fmaxf(bi.y, bj.y);
            float yy2 = fminf(bi.z, bj.z);
            float xx2 = fminf(bi.w, bj.w);
            float inter = fmaxf(yy2 - yy1, 0.0f) * fmaxf(xx2 - xx1, 0.0f);
            float aj = (bj.z - bj.x) * (bj.w - bj.y);
            float iou = inter / (ai + aj - inter + 1e-12f);
            if (iou > NMST) sup[jr] = 1;
        }
        if (tid == 0) { out_rank[nsurv] = i; nsurv += 1; }
    }
    __syncthreads();

    const int ns = nsurv;
    for (int o = tid; o < MAXI; o += 256) {
        float v0=0.f,v1=0.f,v2=0.f,v3=0.f,v4=0.f,v5=0.f;
        if (o < ns) {
            int r = out_rank[o];
            unsigned long long kr = key[r];
            int orr = (int)(0xFFFFFFFFu - (unsigned)(kr & 0xFFFFFFFFull));
            float4 bo = sbox[orr];
            v0 = bo.x; v1 = bo.y; v2 = bo.z; v3 = bo.w;
            v4 = (float)scls[orr];
            v5 = unordf((unsigned)(kr >> 32));
        }
        float* op = out + ((size_t)b * MAXI + o) * 6;
        op[0]=v0; op[1]=v1; op[2]=v2; op[3]=v3; op[4]=v4; op[5]=v5;
    }
}

extern "C" void kernel_launch(void* const* d_in, const int* in_sizes, int n_in,
                              void* d_out, int out_size, void* d_ws, size_t ws_size,
                              hipStream_t stream) {
    const float* rois   = (const float*)d_in[0];
    const float* probs  = (const float*)d_in[1];
    const float* deltas = (const float*)d_in[2];
    const float* meta   = (const float*)d_in[3];
    float* out = (float*)d_out;
    (void)in_sizes; (void)n_in; (void)out_size;

    if (ws_size >= (size_t)WS_NEEDED) {
        char* ws = (char*)d_ws;
        float4* wbox = (float4*)(ws + WS_BOX_OFF);
        unsigned long long* wkey = (unsigned long long*)(ws + WS_KEY_OFF);
        unsigned int* done = (unsigned int*)(ws + WS_DONE_OFF);
        // zero the 16 per-image completion counters each call (deterministic;
        // graph-capturable async node).
        hipMemsetAsync(done, 0, 64, stream);
        fused_kernel<<<NB + NPREP, BT, 0, stream>>>(rois, probs, deltas, meta,
                                                    wbox, wkey, done, out);
    } else {
        det_mono_kernel<<<NB, 256, 0, stream>>>(rois, probs, deltas, meta, out);
    }
}

// Round 8
// 28.789 us; speedup vs baseline: 6.1941x; 6.1941x over previous
//
#include <hip/hip_runtime.h>

#define NB    16      // batch
#define NN    2000    // rois per image
#define NC    81      // classes
#define NPAD  2048    // padded sort size (worst case)
#define MAXI  100     // max instances
#define MINC  0.7f
#define NMST  0.3f
#define NEGV  -1000000000.0f
#define BTP   256     // prep block threads
#define BT    512     // det2 block threads
#define NWAVE (BT/64)

#define WS_BOX_OFF  0
#define WS_KEY_OFF  (NB * NN * 16)                 // 512000
#define WS_NEEDED   (WS_KEY_OFF + NB * NN * 8)     // 768000

// monotone order-preserving float->uint encoding
__device__ __forceinline__ unsigned ordf(float f) {
    unsigned u = __float_as_uint(f);
    return (u & 0x80000000u) ? ~u : (u | 0x80000000u);
}
__device__ __forceinline__ float unordf(unsigned u) {
    unsigned b = (u & 0x80000000u) ? (u ^ 0x80000000u) : ~u;
    return __uint_as_float(b);
}

// register bitonic compare-exchange across lanes (64-bit key via 2x shfl_xor)
__device__ __forceinline__ unsigned long long cx64(unsigned long long k, int j,
                                                   bool desc, int lane) {
    unsigned lo = __shfl_xor((unsigned)k, j, 64);
    unsigned hi = __shfl_xor((unsigned)(k >> 32), j, 64);
    unsigned long long p = ((unsigned long long)hi << 32) | lo;
    bool lower    = ((lane & j) == 0);
    bool take_max = (lower == desc);
    return ((p > k) == take_max) ? p : k;
}

// key layout: [63:32] ordf(masked_score) | [18:8] (2047 - i) | [7:0] class
// (bits below the unique inv-index can never affect the stable sort order)

// ---------------- kernel A: grid-wide prep (argmax, refine, clip, key) ----
__global__ __launch_bounds__(BTP)
void prep_kernel(const float* __restrict__ rois,
                 const float* __restrict__ probs,
                 const float* __restrict__ deltas,
                 const float* __restrict__ meta,
                 float4* __restrict__ wbox,
                 unsigned long long* __restrict__ wkey) {
    const int g = threadIdx.x >> 4;
    const int l = threadIdx.x & 15;
    const int r = blockIdx.x * 16 + g;          // flat roi id < 32000
    const int b = r / NN;
    const int i = r - b * NN;

    const float* prow = probs + (size_t)r * NC;
    float best = -1.0f; int cb = 0;
    for (int c = l; c < NC; c += 16) {
        float p = prow[c];
        if (p > best) { best = p; cb = c; }     // ascending c => first-max kept
    }
    #pragma unroll
    for (int off = 8; off; off >>= 1) {
        float pb = __shfl_xor(best, off, 16);
        int   co = __shfl_xor(cb,   off, 16);
        if (pb > best || (pb == best && co < cb)) { best = pb; cb = co; }
    }

    if (l == 0) {
        const int MS = 12 + NC;
        const float ih = meta[4], iw = meta[5];
        const float sy = ih - 1.0f, sx = iw - 1.0f;
        const float wy1 = (meta[(size_t)b * MS + 7]        ) / sy;
        const float wx1 = (meta[(size_t)b * MS + 8]        ) / sx;
        const float wy2 = (meta[(size_t)b * MS + 9]  - 1.0f) / sy;
        const float wx2 = (meta[(size_t)b * MS + 10] - 1.0f) / sx;

        const float* drow = deltas + ((size_t)r * NC + cb) * 4;
        float dy = drow[0] * 0.1f, dx = drow[1] * 0.1f;
        float dh = drow[2] * 0.2f, dw = drow[3] * 0.2f;

        const float4 r4 = *(const float4*)(rois + (size_t)r * 4);
        float h  = r4.z - r4.x;
        float w  = r4.w - r4.y;
        float cy = r4.x + 0.5f * h;
        float cx = r4.y + 0.5f * w;
        cy = cy + dy * h;
        cx = cx + dx * w;
        h  = h * expf(dh);
        w  = w * expf(dw);
        float y1 = fminf(fmaxf(cy - 0.5f * h, wy1), wy2);
        float x1 = fminf(fmaxf(cx - 0.5f * w, wx1), wx2);
        float y2 = fminf(fmaxf(cy + 0.5f * h, wy1), wy2);
        float x2 = fminf(fmaxf(cx + 0.5f * w, wx1), wx2);

        wbox[r] = make_float4(y1, x1, y2, x2);
        bool kept = (cb > 0) && (best >= MINC);
        float msc = kept ? best : NEGV;
        wkey[r] = ((unsigned long long)ordf(msc) << 32)
                | (unsigned long long)(((unsigned)(2047 - i) << 8) | (unsigned)cb);
    }
}

// ---------------- kernel B: per-image compact + sort + per-class NMS ------
__global__ __launch_bounds__(BT)
void det2_kernel(const float4* __restrict__ wbox,
                 const unsigned long long* __restrict__ wkey,
                 float* __restrict__ out) {
    __shared__ unsigned long long skey[NPAD];   // 16384 B
    __shared__ float4 sboxR[NPAD];              // 32768 B (boxes by rank)
    __shared__ unsigned char sup[NPAD];         // 2048 B
    __shared__ unsigned short pool[NPAD];       // 4096 B (ranks grouped by class)
    __shared__ int hist[82], cstart[82], cnt[82];
    __shared__ int out_rank[MAXI];
    __shared__ int sK, nsurv;

    const int b    = blockIdx.x;
    const int tid  = threadIdx.x;
    const int lane = tid & 63;
    const int wv   = tid >> 6;

    for (int c = tid; c < 82; c += BT) { hist[c] = 0; cnt[c] = 0; }
    if (tid == 0) { sK = 0; nsurv = 0; }
    __syncthreads();

    // ---- compaction of kept keys: prefetch all 4 keys up-front (one global
    //      latency instead of four serial ones), then ballot-compact.
    const unsigned minc_ord = ordf(MINC);
    unsigned long long kq[4];
    #pragma unroll
    for (int q = 0; q < 4; ++q) {
        int i = q * BT + tid;
        kq[q] = (i < NN) ? wkey[(size_t)b * NN + i] : 0ull;
    }
    #pragma unroll
    for (int q = 0; q < 4; ++q) {
        bool kept = ((unsigned)(kq[q] >> 32) >= minc_ord);
        unsigned long long m = __ballot(kept);
        int c64 = __popcll(m);
        int basep = 0;
        if (lane == 0 && c64) basep = atomicAdd(&sK, c64);
        basep = __shfl(basep, 0, 64);
        if (kept) skey[basep + __popcll(m & ((1ull << lane) - 1))] = kq[q];
    }
    __syncthreads();
    const int K = sK;
    int P = 0;
    if (K > 0) { P = 64; while (P < K) P <<= 1; }   // min 64 for register sort
    for (int t = K + tid; t < P; t += BT) skey[t] = 0ull;  // pad sorts last (desc)
    __syncthreads();

    // ---- bitonic sort, descending; register-resident chunks + LDS merges ----
    if (P > 0 && P <= 64 * NWAVE) {
        const int nch = P >> 6;                 // 64-elem chunks, one per wave
        const int e   = (wv << 6) + lane;
        unsigned long long k = 0ull;
        if (wv < nch) {
            k = skey[e];
            // full in-register sort of the chunk (network stages kk=2..64)
            #pragma unroll
            for (int kk2 = 2; kk2 <= 64; kk2 <<= 1) {
                #pragma unroll
                for (int j = 32; j; j >>= 1) {
                    if (j < kk2) k = cx64(k, j, ((e & kk2) == 0), lane);
                }
            }
            skey[e] = k;
        }
        __syncthreads();
        // merge levels: cross-wave distances in LDS, tail j<=32 in registers
        for (int kk = 128; kk <= P; kk <<= 1) {
            for (int j = kk >> 1; j >= 64; j >>= 1) {
                int jm = j - 1;
                for (int p = tid; p < (P >> 1); p += BT) {
                    int t  = ((p & ~jm) << 1) | (p & jm);
                    int ix = t + j;
                    unsigned long long a = skey[t], c2 = skey[ix];
                    bool desc = ((t & kk) == 0);
                    if ((a < c2) == desc) { skey[t] = c2; skey[ix] = a; }
                }
                __syncthreads();
            }
            if (wv < nch) {
                k = skey[e];
                const bool desc = ((e & kk) == 0);
                #pragma unroll
                for (int j = 32; j; j >>= 1) k = cx64(k, j, desc, lane);
                skey[e] = k;
            }
            __syncthreads();
        }
    } else if (P > 0) {
        // fallback: plain barrier bitonic (P > 512; rare)
        for (int kk = 2; kk <= P; kk <<= 1) {
            for (int j = kk >> 1; j > 0; j >>= 1) {
                int jm = j - 1;
                for (int p = tid; p < (P >> 1); p += BT) {
                    int t  = ((p & ~jm) << 1) | (p & jm);
                    int ix = t + j;
                    unsigned long long a = skey[t], c2 = skey[ix];
                    bool desc = ((t & kk) == 0);
                    if ((a < c2) == desc) { skey[t] = c2; skey[ix] = a; }
                }
                __syncthreads();
            }
        }
    }

    // ---- gather boxes by rank + class histogram (class from key low byte)
    for (int r2 = tid; r2 < K; r2 += BT) {
        unsigned low = (unsigned)(skey[r2] & 0xFFFFFFFFull);
        int oi = 2047 - (int)((low >> 8) & 0x7FF);
        sboxR[r2] = wbox[(size_t)b * NN + oi];
        sup[r2] = 0;
        atomicAdd(&hist[low & 0xFF], 1);
    }
    __syncthreads();

    // ---- exclusive prefix over 82 class bins (wave 0, 2 bins/lane)
    if (wv == 0) {
        int c0 = 2 * lane, c1 = c0 + 1;
        int h0 = (c0 < 82) ? hist[c0] : 0;
        int h1 = (c1 < 82) ? hist[c1] : 0;
        int s = h0 + h1, sc = s;
        #pragma unroll
        for (int off = 1; off < 64; off <<= 1) {
            int v = __shfl_up(sc, off, 64);
            if (lane >= off) sc += v;
        }
        int excl = sc - s;
        if (c0 < 82) cstart[c0] = excl;
        if (c1 < 82) cstart[c1] = excl + h0;
    }
    __syncthreads();

    // ---- build per-class rank lists in rank order (wave 0, match-any trick)
    if (wv == 0) {
        for (int chunk = 0; chunk < K; chunk += 64) {
            int r2 = chunk + lane;
            bool v = r2 < K;
            int c = v ? (int)(skey[r2] & 0xFF) : 127;
            unsigned long long m = ~0ull;
            #pragma unroll
            for (int kb = 0; kb < 7; ++kb) {
                unsigned long long bk = __ballot((c >> kb) & 1);
                m &= ((c >> kb) & 1) ? bk : ~bk;
            }
            int leader = __ffsll(m) - 1;
            int before = __popcll(m & ((1ull << lane) - 1));
            int basec = 0;
            if (v && lane == leader) basec = atomicAdd(&cnt[c], __popcll(m));
            basec = __shfl(basec, leader, 64);
            if (v) pool[cstart[c] + basec + before] = (unsigned short)r2;
        }
    }
    __syncthreads();

    // ---- per-class NMS: classes strided over 8 waves; register-resident chain
    for (int c = 1 + wv; c < 82; c += NWAVE) {
        int s0 = cstart[c], n = hist[c];
        if (n <= 1) continue;
        if (n <= 64) {
            int ri = 0; float4 bi = make_float4(0.f,0.f,0.f,0.f);
            float ai = 0.f; bool alive = false;
            if (lane < n) {
                ri = pool[s0 + lane];
                bi = sboxR[ri];
                ai = (bi.z - bi.x) * (bi.w - bi.y);
                alive = true;
            }
            unsigned long long cand = __ballot(alive);  // lanes < n, in rank order
            while (cand) {
                int curl = __ffsll(cand) - 1;           // best remaining keeper
                float cy1 = __shfl(bi.x, curl, 64);
                float cx1 = __shfl(bi.y, curl, 64);
                float cy2 = __shfl(bi.z, curl, 64);
                float cx2 = __shfl(bi.w, curl, 64);
                float ca  = __shfl(ai,  curl, 64);
                float yy1 = fmaxf(cy1, bi.x);
                float xx1 = fmaxf(cx1, bi.y);
                float yy2 = fminf(cy2, bi.z);
                float xx2 = fminf(cx2, bi.w);
                float inter = fmaxf(yy2 - yy1, 0.0f) * fmaxf(xx2 - xx1, 0.0f);
                float iou = inter / (ca + ai - inter + 1e-12f);
                bool kill = alive && (lane > curl) && (iou > NMST);
                unsigned long long km = __ballot(kill);
                if (kill) alive = false;
                cand &= ~km;
                cand &= ~(1ull << curl);
            }
            if (lane < n && !alive) sup[ri] = 1;
        } else {
            // fallback: serial-i / parallel-j within the wave (n > 64)
            volatile unsigned char* vsup = sup;
            for (int ii = 0; ii < n; ++ii) {
                int ri = pool[s0 + ii];
                if (vsup[ri]) continue;
                float4 bi = sboxR[ri];
                float ai = (bi.z - bi.x) * (bi.w - bi.y);
                for (int jj = ii + 1 + lane; jj < n; jj += 64) {
                    int rj = pool[s0 + jj];
                    float4 bj = sboxR[rj];
                    float yy1 = fmaxf(bi.x, bj.x);
                    float xx1 = fmaxf(bi.y, bj.y);
                    float yy2 = fminf(bi.z, bj.z);
                    float xx2 = fminf(bi.w, bj.w);
                    float inter = fmaxf(yy2 - yy1, 0.0f) * fmaxf(xx2 - xx1, 0.0f);
                    float aj = (bj.z - bj.x) * (bj.w - bj.y);
                    float iou = inter / (ai + aj - inter + 1e-12f);
                    if (iou > NMST) vsup[rj] = 1;
                }
            }
        }
    }
    __syncthreads();

    // ---- first 100 survivors in rank order (wave 0, ballot compaction)
    if (wv == 0) {
        int total = 0;
        for (int chunk = 0; chunk < K && total < MAXI; chunk += 64) {
            int r2 = chunk + lane;
            bool alivex = (r2 < K) && !sup[r2];
            unsigned long long m = __ballot(alivex);
            int pos = total + __popcll(m & ((1ull << lane) - 1));
            if (alivex && pos < MAXI) out_rank[pos] = r2;
            total += __popcll(m);
        }
        if (lane == 0) nsurv = total < MAXI ? total : MAXI;
    }
    __syncthreads();

    // ---- output [y1,x1,y2,x2,class,score], zero-padded
    const int ns = nsurv;
    for (int o = tid; o < MAXI; o += BT) {
        float v0=0.f,v1=0.f,v2=0.f,v3=0.f,v4=0.f,v5=0.f;
        if (o < ns) {
            int r2 = out_rank[o];
            float4 bo = sboxR[r2];
            unsigned long long kr = skey[r2];
            v0 = bo.x; v1 = bo.y; v2 = bo.z; v3 = bo.w;
            v4 = (float)(int)(kr & 0xFF);
            v5 = unordf((unsigned)(kr >> 32));
        }
        float* op = out + ((size_t)b * MAXI + o) * 6;
        op[0]=v0; op[1]=v1; op[2]=v2; op[3]=v3; op[4]=v4; op[5]=v5;
    }
}

// ---------------- fallback: monolithic kernel (if ws too small) ----
__global__ __launch_bounds__(256)
void det_mono_kernel(const float* __restrict__ rois,
                     const float* __restrict__ probs,
                     const float* __restrict__ deltas,
                     const float* __restrict__ meta,
                     float* __restrict__ out) {
    __shared__ unsigned long long key[NPAD];
    __shared__ float4 sbox[NN];
    __shared__ unsigned char scls[NN];
    __shared__ unsigned char sup[NPAD];
    __shared__ int out_rank[MAXI];
    __shared__ int sK;
    __shared__ int nsurv;

    const int b   = blockIdx.x;
    const int tid = threadIdx.x;
    const int MSTRIDE = 12 + NC;

    if (tid == 0) { sK = 0; nsurv = 0; }

    const float ih = meta[4], iw = meta[5];
    const float sy = ih - 1.0f, sx = iw - 1.0f;
    const float wy1 = (meta[(size_t)b * MSTRIDE + 7]) / sy;
    const float wx1 = (meta[(size_t)b * MSTRIDE + 8]) / sx;
    const float wy2 = (meta[(size_t)b * MSTRIDE + 9] - 1.0f) / sy;
    const float wx2 = (meta[(size_t)b * MSTRIDE + 10] - 1.0f) / sx;

    for (int i = tid; i < NN; i += 256) {
        const float* prow = probs + ((size_t)b * NN + i) * NC;
        float best = prow[0];
        int cb = 0;
        #pragma unroll
        for (int c = 1; c < NC; ++c) {
            float p = prow[c];
            if (p > best) { best = p; cb = c; }
        }
        const float* drow = deltas + (((size_t)b * NN + i) * NC + cb) * 4;
        float dy = drow[0] * 0.1f, dx = drow[1] * 0.1f;
        float dh = drow[2] * 0.2f, dw = drow[3] * 0.2f;
        const float4 r4 = *(const float4*)(rois + ((size_t)b * NN + i) * 4);
        float h  = r4.z - r4.x;
        float w  = r4.w - r4.y;
        float cy = r4.x + 0.5f * h;
        float cx = r4.y + 0.5f * w;
        cy = cy + dy * h;
        cx = cx + dx * w;
        h  = h * expf(dh);
        w  = w * expf(dw);
        float y1 = fminf(fmaxf(cy - 0.5f * h, wy1), wy2);
        float x1 = fminf(fmaxf(cx - 0.5f * w, wx1), wx2);
        float y2 = fminf(fmaxf(cy + 0.5f * h, wy1), wy2);
        float x2 = fminf(fmaxf(cx + 0.5f * w, wx1), wx2);
        sbox[i] = make_float4(y1, x1, y2, x2);
        scls[i] = (unsigned char)cb;
        bool kept = (cb > 0) && (best >= MINC);
        float msc = kept ? best : NEGV;
        key[i] = ((unsigned long long)ordf(msc) << 32)
               | (unsigned long long)(0xFFFFFFFFu - (unsigned)i);
    }
    for (int i = NN + tid; i < NPAD; i += 256) key[i] = 0ull;
    __syncthreads();

    for (int k = 2; k <= NPAD; k <<= 1) {
        for (int j = k >> 1; j > 0; j >>= 1) {
            for (int t = tid; t < NPAD; t += 256) {
                int ix = t ^ j;
                if (ix > t) {
                    unsigned long long a = key[t], c = key[ix];
                    bool descend = ((t & k) == 0);
                    if ((a < c) == descend) { key[t] = c; key[ix] = a; }
                }
            }
            __syncthreads();
        }
    }

    const unsigned minc_ord = ordf(MINC);
    for (int r = tid; r < NPAD; r += 256) {
        unsigned su = (unsigned)(key[r] >> 32);
        bool kept = (su >= minc_ord);
        sup[r] = kept ? 0 : 1;
        if (kept) atomicAdd(&sK, 1);
    }
    __syncthreads();
    const int K = sK;

    for (int i = 0; i < K; ++i) {
        __syncthreads();
        if (nsurv >= MAXI) break;
        if (sup[i]) continue;
        unsigned long long ki = key[i];
        int oi = (int)(0xFFFFFFFFu - (unsigned)(ki & 0xFFFFFFFFull));
        float4 bi = sbox[oi];
        int ci = scls[oi];
        float ai = (bi.z - bi.x) * (bi.w - bi.y);
        for (int jr = i + 1 + tid; jr < K; jr += 256) {
            int oj = (int)(0xFFFFFFFFu - (unsigned)(key[jr] & 0xFFFFFFFFull));
            if ((int)scls[oj] != ci) continue;
            float4 bj = sbox[oj];
            float yy1 = fmaxf(bi.x, bj.x);
            float xx1 = fmaxf(bi.y, bj.y);
            float yy2 = fminf(bi.z, bj.z);
            float xx2 = fminf(bi.w, bj.w);
            float inter = fmaxf(yy2 - yy1, 0.0f) * fmaxf(xx2 - xx1, 0.0f);
            float aj = (bj.z - bj.x) * (bj.w - bj.y);
            float iou = inter / (ai + aj - inter + 1e-12f);
            if (iou > NMST) sup[jr] = 1;
        }
        if (tid == 0) { out_rank[nsurv] = i; nsurv += 1; }
    }
    __syncthreads();

    const int ns = nsurv;
    for (int o = tid; o < MAXI; o += 256) {
        float v0=0.f,v1=0.f,v2=0.f,v3=0.f,v4=0.f,v5=0.f;
        if (o < ns) {
            int r = out_rank[o];
            unsigned long long kr = key[r];
            int orr = (int)(0xFFFFFFFFu - (unsigned)(kr & 0xFFFFFFFFull));
            float4 bo = sbox[orr];
            v0 = bo.x; v1 = bo.y; v2 = bo.z; v3 = bo.w;
            v4 = (float)scls[orr];
            v5 = unordf((unsigned)(kr >> 32));
        }
        float* op = out + ((size_t)b * MAXI + o) * 6;
        op[0]=v0; op[1]=v1; op[2]=v2; op[3]=v3; op[4]=v4; op[5]=v5;
    }
}

extern "C" void kernel_launch(void* const* d_in, const int* in_sizes, int n_in,
                              void* d_out, int out_size, void* d_ws, size_t ws_size,
                              hipStream_t stream) {
    const float* rois   = (const float*)d_in[0];
    const float* probs  = (const float*)d_in[1];
    const float* deltas = (const float*)d_in[2];
    const float* meta   = (const float*)d_in[3];
    float* out = (float*)d_out;
    (void)in_sizes; (void)n_in; (void)out_size;

    if (ws_size >= (size_t)WS_NEEDED) {
        char* ws = (char*)d_ws;
        float4* wbox = (float4*)(ws + WS_BOX_OFF);
        unsigned long long* wkey = (unsigned long long*)(ws + WS_KEY_OFF);
        prep_kernel<<<(NB * NN) / 16, BTP, 0, stream>>>(rois, probs, deltas, meta,
                                                        wbox, wkey);
        det2_kernel<<<NB, BT, 0, stream>>>(wbox, wkey, out);
    } else {
        det_mono_kernel<<<NB, 256, 0, stream>>>(rois, probs, deltas, meta, out);
    }
}

// Round 9
// 25.524 us; speedup vs baseline: 6.9863x; 1.1279x over previous
//
#include <hip/hip_runtime.h>

#define NB    16      // batch
#define NN    2000    // rois per image
#define NC    81      // classes
#define NPAD  2048    // padded sort size (worst case)
#define MAXI  100     // max instances
#define MINC  0.7f
#define NMST  0.3f
#define NEGV  -1000000000.0f
#define BTP   256     // prep block threads
#define BT    1024    // det2 block threads (16 waves)
#define NWAVE (BT/64)
#define KQ    ((NN + BT - 1) / BT)   // key prefetch regs per thread (=2)

#define WS_BOX_OFF  0
#define WS_KEY_OFF  (NB * NN * 16)                 // 512000
#define WS_NEEDED   (WS_KEY_OFF + NB * NN * 8)     // 768000

// monotone order-preserving float->uint encoding
__device__ __forceinline__ unsigned ordf(float f) {
    unsigned u = __float_as_uint(f);
    return (u & 0x80000000u) ? ~u : (u | 0x80000000u);
}
__device__ __forceinline__ float unordf(unsigned u) {
    unsigned b = (u & 0x80000000u) ? (u ^ 0x80000000u) : ~u;
    return __uint_as_float(b);
}

// register bitonic compare-exchange across lanes (64-bit key via 2x shfl_xor)
__device__ __forceinline__ unsigned long long cx64(unsigned long long k, int j,
                                                   bool desc, int lane) {
    unsigned lo = __shfl_xor((unsigned)k, j, 64);
    unsigned hi = __shfl_xor((unsigned)(k >> 32), j, 64);
    unsigned long long p = ((unsigned long long)hi << 32) | lo;
    bool lower    = ((lane & j) == 0);
    bool take_max = (lower == desc);
    return ((p > k) == take_max) ? p : k;
}

// key layout: [63:32] ordf(masked_score) | [18:8] (2047 - i) | [7:0] class
// (bits below the unique inv-index can never affect the stable sort order)

// ---------------- kernel A: grid-wide prep (argmax, refine, clip, key) ----
__global__ __launch_bounds__(BTP)
void prep_kernel(const float* __restrict__ rois,
                 const float* __restrict__ probs,
                 const float* __restrict__ deltas,
                 const float* __restrict__ meta,
                 float4* __restrict__ wbox,
                 unsigned long long* __restrict__ wkey) {
    const int g = threadIdx.x >> 4;
    const int l = threadIdx.x & 15;
    const int r = blockIdx.x * 16 + g;          // flat roi id < 32000
    const int b = r / NN;
    const int i = r - b * NN;

    const float* prow = probs + (size_t)r * NC;
    float best = -1.0f; int cb = 0;
    for (int c = l; c < NC; c += 16) {
        float p = prow[c];
        if (p > best) { best = p; cb = c; }     // ascending c => first-max kept
    }
    #pragma unroll
    for (int off = 8; off; off >>= 1) {
        float pb = __shfl_xor(best, off, 16);
        int   co = __shfl_xor(cb,   off, 16);
        if (pb > best || (pb == best && co < cb)) { best = pb; cb = co; }
    }

    if (l == 0) {
        const int MS = 12 + NC;
        const float ih = meta[4], iw = meta[5];
        const float sy = ih - 1.0f, sx = iw - 1.0f;
        const float wy1 = (meta[(size_t)b * MS + 7]        ) / sy;
        const float wx1 = (meta[(size_t)b * MS + 8]        ) / sx;
        const float wy2 = (meta[(size_t)b * MS + 9]  - 1.0f) / sy;
        const float wx2 = (meta[(size_t)b * MS + 10] - 1.0f) / sx;

        const float* drow = deltas + ((size_t)r * NC + cb) * 4;
        float dy = drow[0] * 0.1f, dx = drow[1] * 0.1f;
        float dh = drow[2] * 0.2f, dw = drow[3] * 0.2f;

        const float4 r4 = *(const float4*)(rois + (size_t)r * 4);
        float h  = r4.z - r4.x;
        float w  = r4.w - r4.y;
        float cy = r4.x + 0.5f * h;
        float cx = r4.y + 0.5f * w;
        cy = cy + dy * h;
        cx = cx + dx * w;
        h  = h * expf(dh);
        w  = w * expf(dw);
        float y1 = fminf(fmaxf(cy - 0.5f * h, wy1), wy2);
        float x1 = fminf(fmaxf(cx - 0.5f * w, wx1), wx2);
        float y2 = fminf(fmaxf(cy + 0.5f * h, wy1), wy2);
        float x2 = fminf(fmaxf(cx + 0.5f * w, wx1), wx2);

        wbox[r] = make_float4(y1, x1, y2, x2);
        bool kept = (cb > 0) && (best >= MINC);
        float msc = kept ? best : NEGV;
        wkey[r] = ((unsigned long long)ordf(msc) << 32)
                | (unsigned long long)(((unsigned)(2047 - i) << 8) | (unsigned)cb);
    }
}

// ---------------- kernel B: per-image compact + sort + per-class NMS ------
__global__ __launch_bounds__(BT)
void det2_kernel(const float4* __restrict__ wbox,
                 const unsigned long long* __restrict__ wkey,
                 float* __restrict__ out) {
    __shared__ unsigned long long skey[NPAD];   // 16384 B
    __shared__ float4 sboxR[NPAD];              // 32768 B (boxes by rank)
    __shared__ unsigned char sup[NPAD];         // 2048 B
    __shared__ unsigned short pool[NPAD];       // 4096 B (ranks grouped by class)
    __shared__ int hist[82], cstart[82], cnt[82];
    __shared__ int out_rank[MAXI];
    __shared__ int sK, nsurv;

    const int b    = blockIdx.x;
    const int tid  = threadIdx.x;
    const int lane = tid & 63;
    const int wv   = tid >> 6;

    for (int c = tid; c < 82; c += BT) { hist[c] = 0; cnt[c] = 0; }
    if (tid == 0) { sK = 0; nsurv = 0; }
    __syncthreads();

    // ---- compaction of kept keys: prefetch all keys up-front (one global
    //      latency), then ballot-compact (2 rounds at BT=1024).
    const unsigned minc_ord = ordf(MINC);
    unsigned long long kq[KQ];
    #pragma unroll
    for (int q = 0; q < KQ; ++q) {
        int i = q * BT + tid;
        kq[q] = (i < NN) ? wkey[(size_t)b * NN + i] : 0ull;
    }
    #pragma unroll
    for (int q = 0; q < KQ; ++q) {
        bool kept = ((unsigned)(kq[q] >> 32) >= minc_ord);
        unsigned long long m = __ballot(kept);
        int c64 = __popcll(m);
        int basep = 0;
        if (lane == 0 && c64) basep = atomicAdd(&sK, c64);
        basep = __shfl(basep, 0, 64);
        if (kept) skey[basep + __popcll(m & ((1ull << lane) - 1))] = kq[q];
    }
    __syncthreads();
    const int K = sK;
    int P = 0;
    if (K > 0) { P = 64; while (P < K) P <<= 1; }   // min 64 for register sort
    for (int t = K + tid; t < P; t += BT) skey[t] = 0ull;  // pad sorts last (desc)
    __syncthreads();

    // ---- bitonic sort, descending; register-resident chunks + LDS merges ----
    if (P > 0 && P <= 64 * NWAVE) {
        const int nch = P >> 6;                 // 64-elem chunks, one per wave
        const int e   = (wv << 6) + lane;
        unsigned long long k = 0ull;
        if (wv < nch) {
            k = skey[e];
            // full in-register sort of the chunk (network stages kk=2..64)
            #pragma unroll
            for (int kk2 = 2; kk2 <= 64; kk2 <<= 1) {
                #pragma unroll
                for (int j = 32; j; j >>= 1) {
                    if (j < kk2) k = cx64(k, j, ((e & kk2) == 0), lane);
                }
            }
            skey[e] = k;
        }
        __syncthreads();
        // merge levels: cross-wave distances in LDS, tail j<=32 in registers
        for (int kk = 128; kk <= P; kk <<= 1) {
            for (int j = kk >> 1; j >= 64; j >>= 1) {
                int jm = j - 1;
                for (int p = tid; p < (P >> 1); p += BT) {
                    int t  = ((p & ~jm) << 1) | (p & jm);
                    int ix = t + j;
                    unsigned long long a = skey[t], c2 = skey[ix];
                    bool desc = ((t & kk) == 0);
                    if ((a < c2) == desc) { skey[t] = c2; skey[ix] = a; }
                }
                __syncthreads();
            }
            if (wv < nch) {
                k = skey[e];
                const bool desc = ((e & kk) == 0);
                #pragma unroll
                for (int j = 32; j; j >>= 1) k = cx64(k, j, desc, lane);
                skey[e] = k;
            }
            __syncthreads();
        }
    } else if (P > 0) {
        // fallback: plain barrier bitonic (P > 1024; rare)
        for (int kk = 2; kk <= P; kk <<= 1) {
            for (int j = kk >> 1; j > 0; j >>= 1) {
                int jm = j - 1;
                for (int p = tid; p < (P >> 1); p += BT) {
                    int t  = ((p & ~jm) << 1) | (p & jm);
                    int ix = t + j;
                    unsigned long long a = skey[t], c2 = skey[ix];
                    bool desc = ((t & kk) == 0);
                    if ((a < c2) == desc) { skey[t] = c2; skey[ix] = a; }
                }
                __syncthreads();
            }
        }
    }

    // ---- gather boxes by rank + class histogram (class from key low byte)
    for (int r2 = tid; r2 < K; r2 += BT) {
        unsigned low = (unsigned)(skey[r2] & 0xFFFFFFFFull);
        int oi = 2047 - (int)((low >> 8) & 0x7FF);
        sboxR[r2] = wbox[(size_t)b * NN + oi];
        sup[r2] = 0;
        atomicAdd(&hist[low & 0xFF], 1);
    }
    __syncthreads();

    // ---- exclusive prefix over 82 class bins (wave 0, 2 bins/lane)
    if (wv == 0) {
        int c0 = 2 * lane, c1 = c0 + 1;
        int h0 = (c0 < 82) ? hist[c0] : 0;
        int h1 = (c1 < 82) ? hist[c1] : 0;
        int s = h0 + h1, sc = s;
        #pragma unroll
        for (int off = 1; off < 64; off <<= 1) {
            int v = __shfl_up(sc, off, 64);
            if (lane >= off) sc += v;
        }
        int excl = sc - s;
        if (c0 < 82) cstart[c0] = excl;
        if (c1 < 82) cstart[c1] = excl + h0;
    }
    __syncthreads();

    // ---- build per-class rank lists in rank order (wave 0, match-any trick)
    if (wv == 0) {
        for (int chunk = 0; chunk < K; chunk += 64) {
            int r2 = chunk + lane;
            bool v = r2 < K;
            int c = v ? (int)(skey[r2] & 0xFF) : 127;
            unsigned long long m = ~0ull;
            #pragma unroll
            for (int kb = 0; kb < 7; ++kb) {
                unsigned long long bk = __ballot((c >> kb) & 1);
                m &= ((c >> kb) & 1) ? bk : ~bk;
            }
            int leader = __ffsll(m) - 1;
            int before = __popcll(m & ((1ull << lane) - 1));
            int basec = 0;
            if (v && lane == leader) basec = atomicAdd(&cnt[c], __popcll(m));
            basec = __shfl(basec, leader, 64);
            if (v) pool[cstart[c] + basec + before] = (unsigned short)r2;
        }
    }
    __syncthreads();

    // ---- per-class NMS: classes strided over 16 waves; register-resident chain
    for (int c = 1 + wv; c < 82; c += NWAVE) {
        int s0 = cstart[c], n = hist[c];
        if (n <= 1) continue;
        if (n <= 64) {
            int ri = 0; float4 bi = make_float4(0.f,0.f,0.f,0.f);
            float ai = 0.f; bool alive = false;
            if (lane < n) {
                ri = pool[s0 + lane];
                bi = sboxR[ri];
                ai = (bi.z - bi.x) * (bi.w - bi.y);
                alive = true;
            }
            unsigned long long cand = __ballot(alive);  // lanes < n, in rank order
            while (cand) {
                int curl = __ffsll(cand) - 1;           // best remaining keeper
                float cy1 = __shfl(bi.x, curl, 64);
                float cx1 = __shfl(bi.y, curl, 64);
                float cy2 = __shfl(bi.z, curl, 64);
                float cx2 = __shfl(bi.w, curl, 64);
                float ca  = __shfl(ai,  curl, 64);
                float yy1 = fmaxf(cy1, bi.x);
                float xx1 = fmaxf(cx1, bi.y);
                float yy2 = fminf(cy2, bi.z);
                float xx2 = fminf(cx2, bi.w);
                float inter = fmaxf(yy2 - yy1, 0.0f) * fmaxf(xx2 - xx1, 0.0f);
                float iou = inter / (ca + ai - inter + 1e-12f);
                bool kill = alive && (lane > curl) && (iou > NMST);
                unsigned long long km = __ballot(kill);
                if (kill) alive = false;
                cand &= ~km;
                cand &= ~(1ull << curl);
            }
            if (lane < n && !alive) sup[ri] = 1;
        } else {
            // fallback: serial-i / parallel-j within the wave (n > 64)
            volatile unsigned char* vsup = sup;
            for (int ii = 0; ii < n; ++ii) {
                int ri = pool[s0 + ii];
                if (vsup[ri]) continue;
                float4 bi = sboxR[ri];
                float ai = (bi.z - bi.x) * (bi.w - bi.y);
                for (int jj = ii + 1 + lane; jj < n; jj += 64) {
                    int rj = pool[s0 + jj];
                    float4 bj = sboxR[rj];
                    float yy1 = fmaxf(bi.x, bj.x);
                    float xx1 = fmaxf(bi.y, bj.y);
                    float yy2 = fminf(bi.z, bj.z);
                    float xx2 = fminf(bi.w, bj.w);
                    float inter = fmaxf(yy2 - yy1, 0.0f) * fmaxf(xx2 - xx1, 0.0f);
                    float aj = (bj.z - bj.x) * (bj.w - bj.y);
                    float iou = inter / (ai + aj - inter + 1e-12f);
                    if (iou > NMST) vsup[rj] = 1;
                }
            }
        }
    }
    __syncthreads();

    // ---- first 100 survivors in rank order (wave 0, ballot compaction)
    if (wv == 0) {
        int total = 0;
        for (int chunk = 0; chunk < K && total < MAXI; chunk += 64) {
            int r2 = chunk + lane;
            bool alivex = (r2 < K) && !sup[r2];
            unsigned long long m = __ballot(alivex);
            int pos = total + __popcll(m & ((1ull << lane) - 1));
            if (alivex && pos < MAXI) out_rank[pos] = r2;
            total += __popcll(m);
        }
        if (lane == 0) nsurv = total < MAXI ? total : MAXI;
    }
    __syncthreads();

    // ---- output [y1,x1,y2,x2,class,score], zero-padded
    const int ns = nsurv;
    for (int o = tid; o < MAXI; o += BT) {
        float v0=0.f,v1=0.f,v2=0.f,v3=0.f,v4=0.f,v5=0.f;
        if (o < ns) {
            int r2 = out_rank[o];
            float4 bo = sboxR[r2];
            unsigned long long kr = skey[r2];
            v0 = bo.x; v1 = bo.y; v2 = bo.z; v3 = bo.w;
            v4 = (float)(int)(kr & 0xFF);
            v5 = unordf((unsigned)(kr >> 32));
        }
        float* op = out + ((size_t)b * MAXI + o) * 6;
        op[0]=v0; op[1]=v1; op[2]=v2; op[3]=v3; op[4]=v4; op[5]=v5;
    }
}

// ---------------- fallback: monolithic kernel (if ws too small) ----
__global__ __launch_bounds__(256)
void det_mono_kernel(const float* __restrict__ rois,
                     const float* __restrict__ probs,
                     const float* __restrict__ deltas,
                     const float* __restrict__ meta,
                     float* __restrict__ out) {
    __shared__ unsigned long long key[NPAD];
    __shared__ float4 sbox[NN];
    __shared__ unsigned char scls[NN];
    __shared__ unsigned char sup[NPAD];
    __shared__ int out_rank[MAXI];
    __shared__ int sK;
    __shared__ int nsurv;

    const int b   = blockIdx.x;
    const int tid = threadIdx.x;
    const int MSTRIDE = 12 + NC;

    if (tid == 0) { sK = 0; nsurv = 0; }

    const float ih = meta[4], iw = meta[5];
    const float sy = ih - 1.0f, sx = iw - 1.0f;
    const float wy1 = (meta[(size_t)b * MSTRIDE + 7]) / sy;
    const float wx1 = (meta[(size_t)b * MSTRIDE + 8]) / sx;
    const float wy2 = (meta[(size_t)b * MSTRIDE + 9] - 1.0f) / sy;
    const float wx2 = (meta[(size_t)b * MSTRIDE + 10] - 1.0f) / sx;

    for (int i = tid; i < NN; i += 256) {
        const float* prow = probs + ((size_t)b * NN + i) * NC;
        float best = prow[0];
        int cb = 0;
        #pragma unroll
        for (int c = 1; c < NC; ++c) {
            float p = prow[c];
            if (p > best) { best = p; cb = c; }
        }
        const float* drow = deltas + (((size_t)b * NN + i) * NC + cb) * 4;
        float dy = drow[0] * 0.1f, dx = drow[1] * 0.1f;
        float dh = drow[2] * 0.2f, dw = drow[3] * 0.2f;
        const float4 r4 = *(const float4*)(rois + ((size_t)b * NN + i) * 4);
        float h  = r4.z - r4.x;
        float w  = r4.w - r4.y;
        float cy = r4.x + 0.5f * h;
        float cx = r4.y + 0.5f * w;
        cy = cy + dy * h;
        cx = cx + dx * w;
        h  = h * expf(dh);
        w  = w * expf(dw);
        float y1 = fminf(fmaxf(cy - 0.5f * h, wy1), wy2);
        float x1 = fminf(fmaxf(cx - 0.5f * w, wx1), wx2);
        float y2 = fminf(fmaxf(cy + 0.5f * h, wy1), wy2);
        float x2 = fminf(fmaxf(cx + 0.5f * w, wx1), wx2);
        sbox[i] = make_float4(y1, x1, y2, x2);
        scls[i] = (unsigned char)cb;
        bool kept = (cb > 0) && (best >= MINC);
        float msc = kept ? best : NEGV;
        key[i] = ((unsigned long long)ordf(msc) << 32)
               | (unsigned long long)(0xFFFFFFFFu - (unsigned)i);
    }
    for (int i = NN + tid; i < NPAD; i += 256) key[i] = 0ull;
    __syncthreads();

    for (int k = 2; k <= NPAD; k <<= 1) {
        for (int j = k >> 1; j > 0; j >>= 1) {
            for (int t = tid; t < NPAD; t += 256) {
                int ix = t ^ j;
                if (ix > t) {
                    unsigned long long a = key[t], c = key[ix];
                    bool descend = ((t & k) == 0);
                    if ((a < c) == descend) { key[t] = c; key[ix] = a; }
                }
            }
            __syncthreads();
        }
    }

    const unsigned minc_ord = ordf(MINC);
    for (int r = tid; r < NPAD; r += 256) {
        unsigned su = (unsigned)(key[r] >> 32);
        bool kept = (su >= minc_ord);
        sup[r] = kept ? 0 : 1;
        if (kept) atomicAdd(&sK, 1);
    }
    __syncthreads();
    const int K = sK;

    for (int i = 0; i < K; ++i) {
        __syncthreads();
        if (nsurv >= MAXI) break;
        if (sup[i]) continue;
        unsigned long long ki = key[i];
        int oi = (int)(0xFFFFFFFFu - (unsigned)(ki & 0xFFFFFFFFull));
        float4 bi = sbox[oi];
        int ci = scls[oi];
        float ai = (bi.z - bi.x) * (bi.w - bi.y);
        for (int jr = i + 1 + tid; jr < K; jr += 256) {
            int oj = (int)(0xFFFFFFFFu - (unsigned)(key[jr] & 0xFFFFFFFFull));
            if ((int)scls[oj] != ci) continue;
            float4 bj = sbox[oj];
            float yy1 = fmaxf(bi.x, bj.x);
            float xx1 = fmaxf(bi.y, bj.y);
            float yy2 = fminf(bi.z, bj.z);
            float xx2 = fminf(bi.w, bj.w);
            float inter = fmaxf(yy2 - yy1, 0.0f) * fmaxf(xx2 - xx1, 0.0f);
            float aj = (bj.z - bj.x) * (bj.w - bj.y);
            float iou = inter / (ai + aj - inter + 1e-12f);
            if (iou > NMST) sup[jr] = 1;
        }
        if (tid == 0) { out_rank[nsurv] = i; nsurv += 1; }
    }
    __syncthreads();

    const int ns = nsurv;
    for (int o = tid; o < MAXI; o += 256) {
        float v0=0.f,v1=0.f,v2=0.f,v3=0.f,v4=0.f,v5=0.f;
        if (o < ns) {
            int r = out_rank[o];
            unsigned long long kr = key[r];
            int orr = (int)(0xFFFFFFFFu - (unsigned)(kr & 0xFFFFFFFFull));
            float4 bo = sbox[orr];
            v0 = bo.x; v1 = bo.y; v2 = bo.z; v3 = bo.w;
            v4 = (float)scls[orr];
            v5 = unordf((unsigned)(kr >> 32));
        }
        float* op = out + ((size_t)b * MAXI + o) * 6;
        op[0]=v0; op[1]=v1; op[2]=v2; op[3]=v3; op[4]=v4; op[5]=v5;
    }
}

extern "C" void kernel_launch(void* const* d_in, const int* in_sizes, int n_in,
                              void* d_out, int out_size, void* d_ws, size_t ws_size,
                              hipStream_t stream) {
    const float* rois   = (const float*)d_in[0];
    const float* probs  = (const float*)d_in[1];
    const float* deltas = (const float*)d_in[2];
    const float* meta   = (const float*)d_in[3];
    float* out = (float*)d_out;
    (void)in_sizes; (void)n_in; (void)out_size;

    if (ws_size >= (size_t)WS_NEEDED) {
        char* ws = (char*)d_ws;
        float4* wbox = (float4*)(ws + WS_BOX_OFF);
        unsigned long long* wkey = (unsigned long long*)(ws + WS_KEY_OFF);
        prep_kernel<<<(NB * NN) / 16, BTP, 0, stream>>>(rois, probs, deltas, meta,
                                                        wbox, wkey);
        det2_kernel<<<NB, BT, 0, stream>>>(wbox, wkey, out);
    } else {
        det_mono_kernel<<<NB, 256, 0, stream>>>(rois, probs, deltas, meta, out);
    }
}